// Round 5
// baseline (50.841 us; speedup 1.0000x reference)
//
#include <hip/hip_runtime.h>
#include <hip/hip_bf16.h>

// Flow_6081673691683: Heun flow (10 steps x 2 MLP evals, H=256) + analytic logdet.
// logabsdet = 240*ln(0.95) exactly (two unit shears + det-P^2 mixing per step).
// R5: (a) weights PINNED in VGPRs via asm (R4's VGPR=96 proved remat/reload),
// (b) proper T2 swizzle: bank-aligned strides (512/128/72B) + byte^=(row&7)<<4
// -> 2-way max (R4's stride-576 scheme was still 8-way), (c) M=8 -> 256 blocks
// so all 256 CUs work (was 128), (d) split MFMA chains 8-deep -> 2x4-deep.

typedef unsigned short ushort_t;
typedef float f32x4 __attribute__((ext_vector_type(4)));
typedef short s16x8 __attribute__((ext_vector_type(8)));

#define NB      2048
#define OBS_D   48
#define XDIM    24
#define NSTEPS  10
#define DT      0.1f
#define PP      0.95f

// d_ws layout (ushort / bf16 elements)
#define W1U 0        // 2kt * 16nt * 64 * 8 = 16384
#define W2U 16384    // 8kt * 16nt * 64 * 8 = 65536
#define W3U 81920    // 65536
#define W4U 147456   // 8kt * 64 * 8 = 4096
#define FRAG_BLOCKS 592   // 592*256 == 151552
#define LP_BLOCKS 8       // 8*256 == 2048

// LDS layout (bytes). h-buffers: 16 rows x 512B (8 segs x 64B packed pairs),
// swizzle: column-byte ^= (row&7)<<4  (T2; 2-way max on b128 reads/b32 writes).
// Segment kt, dword d = cols {kt*32+d (lo), kt*32+16+d (hi)}.
#define LDS_BUFA 0        // 8192
#define LDS_BUFB 8192     // 8192
#define LDS_AIN  16384    // 2048 (16 rows x 128B: 2 segs, same swizzle)
#define LDS_PART 18432    // 9216 (8 waves x 16 rows x 72B stride)
#define LDS_TOTAL 27648

__device__ __forceinline__ ushort_t f2bf(float f) {
  unsigned u = __builtin_bit_cast(unsigned, f);
  u += 0x7fffu + ((u >> 16) & 1u);          // RNE
  return (ushort_t)(u >> 16);
}

__device__ __forceinline__ float tanh_fast(float x) {
  float e = __builtin_amdgcn_exp2f(x * 2.885390081777927f);
  return 1.f - 2.f * __builtin_amdgcn_rcpf(1.f + e);
}

// AIN byte offset for (row, col): packed-pair layout + row swizzle
__device__ __forceinline__ int ain_byte(int r, int c) {
  int cb = ((c >> 5) << 6) | ((c & 15) << 2) | (((c >> 4) & 1) << 1);
  return r * 128 + (cb ^ ((r & 7) << 4));
}

// ---------------------------------------------------------------------------
// Prep: weights -> bf16 MFMA B-fragment order (permuted K) + analytic log_probs.
// Fragment (kt, nt, lane l, j) holds W[k_eff][nt*16 + (l&15)],
//   k_eff = kt*32 + 4*(l>>4) + (j>>1) + 16*(j&1)   (matches packed h pairs).
// ---------------------------------------------------------------------------
__global__ void prep_kernel(const float* __restrict__ W1, const float* __restrict__ b1,
                            const float* __restrict__ W2, const float* __restrict__ W3,
                            const float* __restrict__ W4, const float* __restrict__ x0,
                            const int* __restrict__ jac, float* __restrict__ out,
                            ushort_t* __restrict__ ws) {
  int bid = blockIdx.x;
  int tid = threadIdx.x;
  if (bid < FRAG_BLOCKS) {
    int e = bid * 256 + tid;           // 0 .. 151551
    float val = 0.f;
    if (e < 16384) {                   // W1 (61x256 + b1 row 61), K padded to 64
      int kt = e >> 13; int r = e & 8191;
      int nt = r >> 9, l = (r >> 3) & 63, j = r & 7;
      int k = kt * 32 + ((l >> 4) << 2) + (j >> 1) + ((j & 1) << 4);
      int col = nt * 16 + (l & 15);
      val = (k < 61) ? W1[k * 256 + col] : ((k == 61) ? b1[col] : 0.f);
    } else if (e < 81920) {            // W2 (256x256)
      int e2 = e - 16384;
      int kt = e2 >> 13; int r = e2 & 8191;
      int nt = r >> 9, l = (r >> 3) & 63, j = r & 7;
      int k = kt * 32 + ((l >> 4) << 2) + (j >> 1) + ((j & 1) << 4);
      int col = nt * 16 + (l & 15);
      val = W2[k * 256 + col];
    } else if (e < 147456) {           // W3 (256x256)
      int e2 = e - 81920;
      int kt = e2 >> 13; int r = e2 & 8191;
      int nt = r >> 9, l = (r >> 3) & 63, j = r & 7;
      int k = kt * 32 + ((l >> 4) << 2) + (j >> 1) + ((j & 1) << 4);
      int col = nt * 16 + (l & 15);
      val = W3[k * 256 + col];
    } else {                           // W4 (256x12), N padded to 16
      int e2 = e - 147456;
      int kt = e2 >> 9; int r = e2 & 511;
      int l = (r >> 3) & 63, j = r & 7;
      int k = kt * 32 + ((l >> 4) << 2) + (j >> 1) + ((j & 1) << 4);
      int col = l & 15;
      val = (col < 12) ? W4[k * 12 + col] : 0.f;
    }
    ws[e] = f2bf(val);
  } else {
    int s = (bid - FRAG_BLOCKS) * 256 + tid;   // 0..2047
    float acc = 0.f;
    #pragma unroll 4
    for (int j = 0; j < XDIM; ++j) { float v = x0[s * XDIM + j]; acc += v * v; }
    // -0.5*d*ln(2pi) = -22.054524796912143 ; -240*ln(0.95) = +12.310390653012128
    float C = (jac[0] != 0) ? -9.744134143900015f : -22.054524796912143f;
    out[NB * XDIM + s] = -0.5f * acc + C;
  }
}

// ---------------------------------------------------------------------------
// Main: 256 blocks x 512 threads (8 waves), 8 samples/block (M rows 0..7 real,
// 8..15 pad). Wave wv owns hidden cols [32wv, 32wv+32). Weights pinned in VGPRs.
// ---------------------------------------------------------------------------
__global__ __launch_bounds__(512, 2) void flow_main(
    const float* __restrict__ obs, const float* __restrict__ x0,
    const float* __restrict__ b2g, const float* __restrict__ b3g,
    const float* __restrict__ b4g, const ushort_t* __restrict__ ws,
    float* __restrict__ out) {
  __shared__ char lds[LDS_TOTAL];
  const int tid  = threadIdx.x;
  const int lane = tid & 63;
  const int wv   = tid >> 6;
  const int g    = lane >> 4;       // K-group 0..3
  const int ar   = lane & 15;       // A row / C-D col within tile
  const int row0 = blockIdx.x * 8;
  const int sw   = (ar & 7) << 4;   // read-side swizzle (row = ar)
  const int hwc  = wv * 64 + ar * 4;            // h-write col-byte (pre-swizzle)
  const int rs   = tid >> 4, cs = tid & 15;     // reduce role (tid<256)

  // --- zero AIN (512 dwords == 512 threads) ---
  ((unsigned*)(lds + LDS_AIN))[tid] = 0u;
  __syncthreads();

  // --- obs (rows 0..7), bias-one col 61, y-seed cols 0..11 ---
  if (tid < 8 * OBS_D) {
    int r = tid / OBS_D, o = tid - r * OBS_D;
    *(ushort_t*)(lds + LDS_AIN + ain_byte(r, 12 + o)) = f2bf(obs[(row0 + r) * OBS_D + o]);
  }
  if (tid < 16)   // col 61 = 1.0 (bias row); col 60 (t) stays 0 for step 0
    *(ushort_t*)(lds + LDS_AIN + tid * 128 + (118 ^ ((tid & 7) << 4))) = (ushort_t)0x3F80;

  float zr = 0.f, yr = 0.f, zir = 0.f;
  if (tid < 256 && cs < 12 && rs < 8) {
    zr = x0[(row0 + rs) * XDIM + cs];
    yr = x0[(row0 + rs) * XDIM + 12 + cs];
    *(ushort_t*)(lds + LDS_AIN + rs * 128 + ((cs * 4) ^ ((rs & 7) << 4))) = f2bf(yr);
  }

  // --- weight fragments -> VGPRs, PINNED (RER4: VGPR=96 proved remat) ---
  s16x8 w1r[2][2], w2r[8][2], w3r[8][2], w4r;
  #pragma unroll
  for (int kt = 0; kt < 2; ++kt)
    #pragma unroll
    for (int n = 0; n < 2; ++n)
      w1r[kt][n] = *(const s16x8*)(ws + W1U + (((kt * 16) + (2 * wv + n)) * 64 + lane) * 8);
  #pragma unroll
  for (int kt = 0; kt < 8; ++kt)
    #pragma unroll
    for (int n = 0; n < 2; ++n) {
      w2r[kt][n] = *(const s16x8*)(ws + W2U + (((kt * 16) + (2 * wv + n)) * 64 + lane) * 8);
      w3r[kt][n] = *(const s16x8*)(ws + W3U + (((kt * 16) + (2 * wv + n)) * 64 + lane) * 8);
    }
  w4r = *(const s16x8*)(ws + W4U + (wv * 64 + lane) * 8);
  #pragma unroll
  for (int kt = 0; kt < 2; ++kt)
    asm volatile("" : "+v"(w1r[kt][0]), "+v"(w1r[kt][1]));
  #pragma unroll
  for (int kt = 0; kt < 8; ++kt)
    asm volatile("" : "+v"(w2r[kt][0]), "+v"(w2r[kt][1]), "+v"(w3r[kt][0]), "+v"(w3r[kt][1]));
  asm volatile("" : "+v"(w4r));

  float b2r[2], b3r[2];
  #pragma unroll
  for (int n = 0; n < 2; ++n) {
    b2r[n] = b2g[(2 * wv + n) * 16 + ar];
    b3r[n] = b3g[(2 * wv + n) * 16 + ar];
  }
  const float b4v = (cs < 12) ? b4g[cs] : 0.f;

  __syncthreads();

  const f32x4 z4 = {0.f, 0.f, 0.f, 0.f};

  for (int i = 0; i < NSTEPS; ++i) {
    #pragma unroll
    for (int ev = 0; ev < 2; ++ev) {
      // ---- L1: [act|obs|t|1] @ W1 (K=64, b1 folded) ----
      f32x4 acc0 = z4, acc1 = z4;
      #pragma unroll
      for (int kt = 0; kt < 2; ++kt) {
        s16x8 a = *(const s16x8*)(lds + LDS_AIN + ar * 128 + ((kt * 64 + g * 16) ^ sw));
        acc0 = __builtin_amdgcn_mfma_f32_16x16x32_bf16(a, w1r[kt][0], acc0, 0, 0, 0);
        acc1 = __builtin_amdgcn_mfma_f32_16x16x32_bf16(a, w1r[kt][1], acc1, 0, 0, 0);
      }
      #pragma unroll
      for (int r = 0; r < 4; ++r) {
        int rw = g * 4 + r;
        unsigned p = (unsigned)f2bf(tanh_fast(acc0[r]))
                   | ((unsigned)f2bf(tanh_fast(acc1[r])) << 16);
        *(unsigned*)(lds + LDS_BUFA + rw * 512 + (hwc ^ ((rw & 7) << 4))) = p;
      }
      __syncthreads();

      // ---- L2: h1 @ W2 (pinned frags; 2x4-deep chains for latency) ----
      f32x4 a0a = z4, a0b = z4, a1a = z4, a1b = z4;
      #pragma unroll
      for (int kt = 0; kt < 4; ++kt) {
        s16x8 a = *(const s16x8*)(lds + LDS_BUFA + ar * 512 + ((kt * 64 + g * 16) ^ sw));
        s16x8 b = *(const s16x8*)(lds + LDS_BUFA + ar * 512 + (((kt + 4) * 64 + g * 16) ^ sw));
        a0a = __builtin_amdgcn_mfma_f32_16x16x32_bf16(a, w2r[kt][0], a0a, 0, 0, 0);
        a1a = __builtin_amdgcn_mfma_f32_16x16x32_bf16(a, w2r[kt][1], a1a, 0, 0, 0);
        a0b = __builtin_amdgcn_mfma_f32_16x16x32_bf16(b, w2r[kt + 4][0], a0b, 0, 0, 0);
        a1b = __builtin_amdgcn_mfma_f32_16x16x32_bf16(b, w2r[kt + 4][1], a1b, 0, 0, 0);
      }
      acc0 = a0a + a0b; acc1 = a1a + a1b;
      #pragma unroll
      for (int r = 0; r < 4; ++r) {
        int rw = g * 4 + r;
        unsigned p = (unsigned)f2bf(tanh_fast(acc0[r] + b2r[0]))
                   | ((unsigned)f2bf(tanh_fast(acc1[r] + b2r[1])) << 16);
        *(unsigned*)(lds + LDS_BUFB + rw * 512 + (hwc ^ ((rw & 7) << 4))) = p;
      }
      __syncthreads();

      // ---- L3: h2 @ W3 ----
      a0a = z4; a0b = z4; a1a = z4; a1b = z4;
      #pragma unroll
      for (int kt = 0; kt < 4; ++kt) {
        s16x8 a = *(const s16x8*)(lds + LDS_BUFB + ar * 512 + ((kt * 64 + g * 16) ^ sw));
        s16x8 b = *(const s16x8*)(lds + LDS_BUFB + ar * 512 + (((kt + 4) * 64 + g * 16) ^ sw));
        a0a = __builtin_amdgcn_mfma_f32_16x16x32_bf16(a, w3r[kt][0], a0a, 0, 0, 0);
        a1a = __builtin_amdgcn_mfma_f32_16x16x32_bf16(a, w3r[kt][1], a1a, 0, 0, 0);
        a0b = __builtin_amdgcn_mfma_f32_16x16x32_bf16(b, w3r[kt + 4][0], a0b, 0, 0, 0);
        a1b = __builtin_amdgcn_mfma_f32_16x16x32_bf16(b, w3r[kt + 4][1], a1b, 0, 0, 0);
      }
      acc0 = a0a + a0b; acc1 = a1a + a1b;
      #pragma unroll
      for (int r = 0; r < 4; ++r) {
        int rw = g * 4 + r;
        unsigned p = (unsigned)f2bf(tanh_fast(acc0[r] + b3r[0]))
                   | ((unsigned)f2bf(tanh_fast(acc1[r] + b3r[1])) << 16);
        *(unsigned*)(lds + LDS_BUFA + rw * 512 + (hwc ^ ((rw & 7) << 4))) = p;
      }

      // ---- L4 fused, NO barrier: wave wv's K-slice (seg wv) is wave-local ----
      asm volatile("s_waitcnt lgkmcnt(0)" ::: "memory");
      __builtin_amdgcn_sched_barrier(0);
      {
        s16x8 a = *(const s16x8*)(lds + LDS_BUFA + ar * 512 + ((wv * 64 + g * 16) ^ sw));
        f32x4 p4 = __builtin_amdgcn_mfma_f32_16x16x32_bf16(a, w4r, z4, 0, 0, 0);
        #pragma unroll
        for (int r = 0; r < 4; ++r) {
          int rw = g * 4 + r;
          *(float*)(lds + LDS_PART + wv * 1152 + rw * 72 + ar * 4) = p4[r];
        }
      }
      __syncthreads();

      // ---- reduce + Heun update (threads 0..255; rows 8..15 = harmless pad) ----
      if (tid < 256) {
        float s = b4v;
        #pragma unroll
        for (int w = 0; w < 8; ++w)
          s += *(const float*)(lds + LDS_PART + w * 1152 + rs * 72 + cs * 4);
        if (cs < 12) {
          int byt = rs * 128 + ((cs * 4) ^ ((rs & 7) << 4));
          if (ev == 0) {
            zir = zr + DT * s;
            *(ushort_t*)(lds + LDS_AIN + byt) = f2bf(zir);   // MLP#2 input
          } else {
            float yi = yr + DT * s;
            zr = PP * zir + (1.f - PP) * yi;
            yr = PP * yi + (1.f - PP) * zr;
            *(ushort_t*)(lds + LDS_AIN + byt) = f2bf(yr);    // next MLP#1 input
          }
        }
        if (ev == 1 && cs == 15)   // stage t = (i+1)/10 (col 60) for next step
          *(ushort_t*)(lds + LDS_AIN + rs * 128 + (114 ^ ((rs & 7) << 4))) =
              f2bf((float)(i + 1) * DT);
      }
      __syncthreads();
    }
  }

  // ---- output: action_aug = [z | y] (rows 0..7 only) ----
  if (tid < 256 && cs < 12 && rs < 8) {
    out[(row0 + rs) * XDIM + cs]      = zr;
    out[(row0 + rs) * XDIM + 12 + cs] = yr;
  }
}

extern "C" void kernel_launch(void* const* d_in, const int* in_sizes, int n_in,
                              void* d_out, int out_size, void* d_ws, size_t ws_size,
                              hipStream_t stream) {
  const float* obs = (const float*)d_in[0];
  const float* x0  = (const float*)d_in[1];
  const float* W1  = (const float*)d_in[2];
  const float* b1  = (const float*)d_in[3];
  const float* W2  = (const float*)d_in[4];
  const float* b2  = (const float*)d_in[5];
  const float* W3  = (const float*)d_in[6];
  const float* b3  = (const float*)d_in[7];
  const float* W4  = (const float*)d_in[8];
  const float* b4  = (const float*)d_in[9];
  const int*   jac = (const int*)d_in[10];
  float* out = (float*)d_out;
  ushort_t* ws = (ushort_t*)d_ws;

  prep_kernel<<<FRAG_BLOCKS + LP_BLOCKS, 256, 0, stream>>>(W1, b1, W2, W3, W4, x0, jac, out, ws);
  flow_main<<<256, 512, 0, stream>>>(obs, x0, b2, b3, b4, ws, out);
}

// Round 6
// 48.551 us; speedup vs baseline: 1.0472x; 1.0472x over previous
//
#include <hip/hip_runtime.h>
#include <hip/hip_bf16.h>

// Flow_6081673691683: Heun flow (10 steps x 2 MLP evals, H=256) + analytic logdet.
// logabsdet = 240*ln(0.95) exactly -> jacrev/slogdet eliminated.
// R6: M=16/128 blocks (R5's M=8 padding doubled work for nothing); L1 obs-term
// constant-folded into registers (init-time MFMA); tanh 2log2e scale folded into
// W1/W2/W3/b*; biases in MFMA C-init; v_cvt_pk_bf16_f32 packing; PART layout
// [row][col][wv] for vectorized reduce.

typedef unsigned short ushort_t;
typedef float f32x4 __attribute__((ext_vector_type(4)));
typedef short s16x8 __attribute__((ext_vector_type(8)));

#define NB      2048
#define OBS_D   48
#define XDIM    24
#define NSTEPS  10
#define DT      0.1f
#define PP      0.95f
#define SCL     2.885390081777927f   // 2*log2(e)

// d_ws layout (ushort / bf16 elements)
#define W1U  0        // full W1 frags (init cinit only): 2kt*16nt*512 = 16384
#define W2U  16384    // 65536
#define W3U  81920    // 65536
#define W4U  147456   // 4096 (unscaled)
#define W1AU 151552   // act-only W1 frags (k<12, zero-padded K=32): 16nt*512 = 8192
#define FRAG_BLOCKS 624   // 624*256 == 159744
#define LP_BLOCKS 8

// LDS layout (bytes)
#define LDS_BUFA 0        // 8192 (h1/h3: 16 rows x 512B, XOR (r&7)<<4)
#define LDS_BUFB 8192     // 8192 (h2; rows 0..15 x 128B reused as STG at init)
#define LDS_AIN  16384    // 1024 (16 rows x 64B act-only, XOR (r&3)<<4)
#define LDS_PART 17408    // 8192 (16 row x 16 col x 8 wv f32)
#define LDS_TOTAL 25600

__device__ __forceinline__ ushort_t f2bf(float f) {
  unsigned u = __builtin_bit_cast(unsigned, f);
  u += 0x7fffu + ((u >> 16) & 1u);          // RNE
  return (ushort_t)(u >> 16);
}

// input already scaled by 2*log2(e):  tanh = 1 - 2/(1 + exp2(u))
__device__ __forceinline__ float tanh_s(float u) {
  float e = __builtin_amdgcn_exp2f(u);
  return __builtin_fmaf(-2.f, __builtin_amdgcn_rcpf(1.f + e), 1.f);
}

// packed-pair byte offset within a 128B row (cols 0..63), pre-swizzle
__device__ __forceinline__ int pair_byte(int c) {
  return (((c >> 5) << 6) | ((c & 15) << 2) | (((c >> 4) & 1) << 1));
}

// ---------------------------------------------------------------------------
// Prep: weights -> bf16 MFMA B-fragment order (permuted K) + analytic log_probs.
// k_eff = kt*32 + 4*(l>>4) + (j>>1) + 16*(j&1). W1/W2/W3 (and b1 row) scaled by
// 2*log2(e) so tanh needs no input multiply. W4 unscaled.
// ---------------------------------------------------------------------------
__global__ void prep_kernel(const float* __restrict__ W1, const float* __restrict__ b1,
                            const float* __restrict__ W2, const float* __restrict__ W3,
                            const float* __restrict__ W4, const float* __restrict__ x0,
                            const int* __restrict__ jac, float* __restrict__ out,
                            ushort_t* __restrict__ ws) {
  int bid = blockIdx.x;
  int tid = threadIdx.x;
  if (bid < FRAG_BLOCKS) {
    int e = bid * 256 + tid;           // 0 .. 159743
    float val = 0.f;
    if (e < 16384) {                   // W1 full (61x256 + b1 row 61), scaled
      int kt = e >> 13; int r = e & 8191;
      int nt = r >> 9, l = (r >> 3) & 63, j = r & 7;
      int k = kt * 32 + ((l >> 4) << 2) + (j >> 1) + ((j & 1) << 4);
      int col = nt * 16 + (l & 15);
      val = SCL * ((k < 61) ? W1[k * 256 + col] : ((k == 61) ? b1[col] : 0.f));
    } else if (e < 81920) {            // W2, scaled
      int e2 = e - 16384;
      int kt = e2 >> 13; int r = e2 & 8191;
      int nt = r >> 9, l = (r >> 3) & 63, j = r & 7;
      int k = kt * 32 + ((l >> 4) << 2) + (j >> 1) + ((j & 1) << 4);
      val = SCL * W2[k * 256 + nt * 16 + (l & 15)];
    } else if (e < 147456) {           // W3, scaled
      int e2 = e - 81920;
      int kt = e2 >> 13; int r = e2 & 8191;
      int nt = r >> 9, l = (r >> 3) & 63, j = r & 7;
      int k = kt * 32 + ((l >> 4) << 2) + (j >> 1) + ((j & 1) << 4);
      val = SCL * W3[k * 256 + nt * 16 + (l & 15)];
    } else if (e < 151552) {           // W4 (256x12 -> N pad 16), UNscaled
      int e2 = e - 147456;
      int kt = e2 >> 9; int r = e2 & 511;
      int l = (r >> 3) & 63, j = r & 7;
      int k = kt * 32 + ((l >> 4) << 2) + (j >> 1) + ((j & 1) << 4);
      int col = l & 15;
      val = (col < 12) ? W4[k * 12 + col] : 0.f;
    } else {                           // W1A: act rows only (k<12), K=32, scaled
      int e2 = e - 151552;
      int nt = e2 >> 9; int r = e2 & 511;
      int l = (r >> 3) & 63, j = r & 7;
      int k = ((l >> 4) << 2) + (j >> 1) + ((j & 1) << 4);
      val = (k < 12) ? SCL * W1[k * 256 + nt * 16 + (l & 15)] : 0.f;
    }
    ws[e] = f2bf(val);
  } else {
    int s = (bid - FRAG_BLOCKS) * 256 + tid;   // 0..2047
    float acc = 0.f;
    #pragma unroll 4
    for (int j = 0; j < XDIM; ++j) { float v = x0[s * XDIM + j]; acc += v * v; }
    // -0.5*d*ln(2pi) = -22.054524796912143 ; -240*ln(0.95) = +12.310390653012128
    float C = (jac[0] != 0) ? -9.744134143900015f : -22.054524796912143f;
    out[NB * XDIM + s] = -0.5f * acc + C;
  }
}

// ---------------------------------------------------------------------------
// Main: 128 blocks x 512 threads (8 waves), 16 samples/block.
// ---------------------------------------------------------------------------
__global__ __launch_bounds__(512, 2) void flow_main(
    const float* __restrict__ obs, const float* __restrict__ x0,
    const float* __restrict__ W1g, const float* __restrict__ b2g,
    const float* __restrict__ b3g, const float* __restrict__ b4g,
    const ushort_t* __restrict__ ws, float* __restrict__ out) {
  __shared__ char lds[LDS_TOTAL];
  const int tid  = threadIdx.x;
  const int lane = tid & 63;
  const int wv   = tid >> 6;
  const int g    = lane >> 4;
  const int ar   = lane & 15;
  const int row0 = blockIdx.x * 16;
  const int sw   = (ar & 7) << 4;             // h-buffer read swizzle
  const int rs   = tid >> 4, cs = tid & 15;   // reduce role (tid<256)

  // --- zero STG (BUFB, 16x128B = 512 dw) and AIN (256 dw) ---
  ((unsigned*)(lds + LDS_BUFB))[tid] = 0u;
  if (tid < 256) ((unsigned*)(lds + LDS_AIN))[tid] = 0u;
  __syncthreads();

  // --- fill STG = [0(act)|obs|0(t)|1(bias)] for the cinit MFMA ---
  for (int idx = tid; idx < 16 * OBS_D; idx += 512) {
    int r = idx / OBS_D, o = idx - r * OBS_D;
    int byt = pair_byte(12 + o) ^ ((r & 7) << 4);
    *(ushort_t*)(lds + LDS_BUFB + r * 128 + byt) = f2bf(obs[(row0 + r) * OBS_D + o]);
  }
  if (tid < 16)   // col 61 = 1.0 -> b1 (scaled b1 lives in W1 frag row 61)
    *(ushort_t*)(lds + LDS_BUFB + tid * 128 + (pair_byte(61) ^ ((tid & 7) << 4))) = (ushort_t)0x3F80;

  // --- act seed (y0) into AIN + z/y state regs ---
  float zr = 0.f, yr = 0.f, zir = 0.f;
  if (tid < 256 && cs < 12) {
    zr = x0[(row0 + rs) * XDIM + cs];
    yr = x0[(row0 + rs) * XDIM + 12 + cs];
    *(ushort_t*)(lds + LDS_AIN + rs * 64 + ((cs * 4) ^ ((rs & 3) << 4))) = f2bf(yr);
  }

  // --- weight fragments ---
  s16x8 w1o[2][2];                       // full-W1 (init only)
  s16x8 w1a[2], w2r[8][2], w3r[8][2], w4r;
  #pragma unroll
  for (int kt = 0; kt < 2; ++kt)
    #pragma unroll
    for (int n = 0; n < 2; ++n)
      w1o[kt][n] = *(const s16x8*)(ws + W1U + (((kt * 16) + (2 * wv + n)) * 64 + lane) * 8);
  #pragma unroll
  for (int n = 0; n < 2; ++n)
    w1a[n] = *(const s16x8*)(ws + W1AU + (((2 * wv + n)) * 64 + lane) * 8);
  #pragma unroll
  for (int kt = 0; kt < 8; ++kt)
    #pragma unroll
    for (int n = 0; n < 2; ++n) {
      w2r[kt][n] = *(const s16x8*)(ws + W2U + (((kt * 16) + (2 * wv + n)) * 64 + lane) * 8);
      w3r[kt][n] = *(const s16x8*)(ws + W3U + (((kt * 16) + (2 * wv + n)) * 64 + lane) * 8);
    }
  w4r = *(const s16x8*)(ws + W4U + (wv * 64 + lane) * 8);
  asm volatile("" : "+v"(w1a[0]), "+v"(w1a[1]), "+v"(w4r));
  #pragma unroll
  for (int kt = 0; kt < 8; ++kt)
    asm volatile("" : "+v"(w2r[kt][0]), "+v"(w2r[kt][1]), "+v"(w3r[kt][0]), "+v"(w3r[kt][1]));

  // t-row of W1 (scaled) + biases (scaled; folded into MFMA C-init)
  const float w1t0 = SCL * W1g[60 * 256 + 32 * wv + ar];
  const float w1t1 = SCL * W1g[60 * 256 + 32 * wv + 16 + ar];
  const float b2s0 = SCL * b2g[32 * wv + ar],      b2s1 = SCL * b2g[32 * wv + 16 + ar];
  const float b3s0 = SCL * b3g[32 * wv + ar],      b3s1 = SCL * b3g[32 * wv + 16 + ar];
  const float b4v  = (cs < 12) ? b4g[cs] : 0.f;

  __syncthreads();

  // --- cinit = ([0|obs|0|1] @ W1s) : step-invariant part of L1 pre-activation ---
  const f32x4 z4 = {0.f, 0.f, 0.f, 0.f};
  f32x4 ci0 = z4, ci1 = z4;
  #pragma unroll
  for (int kt = 0; kt < 2; ++kt) {
    s16x8 a = *(const s16x8*)(lds + LDS_BUFB + ar * 128 + ((kt * 64 + g * 16) ^ sw));
    ci0 = __builtin_amdgcn_mfma_f32_16x16x32_bf16(a, w1o[kt][0], ci0, 0, 0, 0);
    ci1 = __builtin_amdgcn_mfma_f32_16x16x32_bf16(a, w1o[kt][1], ci1, 0, 0, 0);
  }
  // (no barrier: BUFB is next written at L2, which is after B1 for every wave)

  for (int i = 0; i < NSTEPS; ++i) {
    const float t = (float)i * DT;
    const float t0 = __builtin_fmaf(t, w1t0, 0.f), t1 = __builtin_fmaf(t, w1t1, 0.f);
    #pragma unroll
    for (int ev = 0; ev < 2; ++ev) {
      // ---- L1: act @ W1a + (cinit + t*w1t)  (1 read, 2 MFMA) ----
      f32x4 acc0 = ci0, acc1 = ci1;
      #pragma unroll
      for (int r = 0; r < 4; ++r) { acc0[r] += t0; acc1[r] += t1; }
      {
        s16x8 a = *(const s16x8*)(lds + LDS_AIN + ar * 64 + ((g * 16) ^ ((ar & 3) << 4)));
        acc0 = __builtin_amdgcn_mfma_f32_16x16x32_bf16(a, w1a[0], acc0, 0, 0, 0);
        acc1 = __builtin_amdgcn_mfma_f32_16x16x32_bf16(a, w1a[1], acc1, 0, 0, 0);
      }
      #pragma unroll
      for (int r = 0; r < 4; ++r) {
        int rw = g * 4 + r;
        float lo = tanh_s(acc0[r]), hi = tanh_s(acc1[r]);
        unsigned p;
        asm("v_cvt_pk_bf16_f32 %0, %1, %2" : "=v"(p) : "v"(lo), "v"(hi));
        *(unsigned*)(lds + LDS_BUFA + rw * 512 + ((wv * 64 + ar * 4) ^ ((rw & 7) << 4))) = p;
      }
      __syncthreads();

      // ---- L2: h1 @ W2 (bias in C-init; 2x4-deep chains) ----
      f32x4 a0a = {b2s0, b2s0, b2s0, b2s0}, a1a = {b2s1, b2s1, b2s1, b2s1};
      f32x4 a0b = z4, a1b = z4;
      #pragma unroll
      for (int kt = 0; kt < 4; ++kt) {
        s16x8 a = *(const s16x8*)(lds + LDS_BUFA + ar * 512 + ((kt * 64 + g * 16) ^ sw));
        s16x8 b = *(const s16x8*)(lds + LDS_BUFA + ar * 512 + (((kt + 4) * 64 + g * 16) ^ sw));
        a0a = __builtin_amdgcn_mfma_f32_16x16x32_bf16(a, w2r[kt][0], a0a, 0, 0, 0);
        a1a = __builtin_amdgcn_mfma_f32_16x16x32_bf16(a, w2r[kt][1], a1a, 0, 0, 0);
        a0b = __builtin_amdgcn_mfma_f32_16x16x32_bf16(b, w2r[kt + 4][0], a0b, 0, 0, 0);
        a1b = __builtin_amdgcn_mfma_f32_16x16x32_bf16(b, w2r[kt + 4][1], a1b, 0, 0, 0);
      }
      acc0 = a0a + a0b; acc1 = a1a + a1b;
      #pragma unroll
      for (int r = 0; r < 4; ++r) {
        int rw = g * 4 + r;
        float lo = tanh_s(acc0[r]), hi = tanh_s(acc1[r]);
        unsigned p;
        asm("v_cvt_pk_bf16_f32 %0, %1, %2" : "=v"(p) : "v"(lo), "v"(hi));
        *(unsigned*)(lds + LDS_BUFB + rw * 512 + ((wv * 64 + ar * 4) ^ ((rw & 7) << 4))) = p;
      }
      __syncthreads();

      // ---- L3: h2 @ W3 ----
      a0a = (f32x4){b3s0, b3s0, b3s0, b3s0}; a1a = (f32x4){b3s1, b3s1, b3s1, b3s1};
      a0b = z4; a1b = z4;
      #pragma unroll
      for (int kt = 0; kt < 4; ++kt) {
        s16x8 a = *(const s16x8*)(lds + LDS_BUFB + ar * 512 + ((kt * 64 + g * 16) ^ sw));
        s16x8 b = *(const s16x8*)(lds + LDS_BUFB + ar * 512 + (((kt + 4) * 64 + g * 16) ^ sw));
        a0a = __builtin_amdgcn_mfma_f32_16x16x32_bf16(a, w3r[kt][0], a0a, 0, 0, 0);
        a1a = __builtin_amdgcn_mfma_f32_16x16x32_bf16(a, w3r[kt][1], a1a, 0, 0, 0);
        a0b = __builtin_amdgcn_mfma_f32_16x16x32_bf16(b, w3r[kt + 4][0], a0b, 0, 0, 0);
        a1b = __builtin_amdgcn_mfma_f32_16x16x32_bf16(b, w3r[kt + 4][1], a1b, 0, 0, 0);
      }
      acc0 = a0a + a0b; acc1 = a1a + a1b;
      #pragma unroll
      for (int r = 0; r < 4; ++r) {
        int rw = g * 4 + r;
        float lo = tanh_s(acc0[r]), hi = tanh_s(acc1[r]);
        unsigned p;
        asm("v_cvt_pk_bf16_f32 %0, %1, %2" : "=v"(p) : "v"(lo), "v"(hi));
        *(unsigned*)(lds + LDS_BUFA + rw * 512 + ((wv * 64 + ar * 4) ^ ((rw & 7) << 4))) = p;
      }

      // ---- L4 fused (no barrier): wave wv's K-slice is the h3 seg it wrote ----
      asm volatile("s_waitcnt lgkmcnt(0)" ::: "memory");
      __builtin_amdgcn_sched_barrier(0);
      {
        s16x8 a = *(const s16x8*)(lds + LDS_BUFA + ar * 512 + ((wv * 64 + g * 16) ^ sw));
        f32x4 p4 = __builtin_amdgcn_mfma_f32_16x16x32_bf16(a, w4r, z4, 0, 0, 0);
        #pragma unroll
        for (int r = 0; r < 4; ++r)
          *(float*)(lds + LDS_PART + (((g * 4 + r) * 128 + ar * 8 + wv) << 2)) = p4[r];
      }
      __syncthreads();

      // ---- reduce + Heun (tid<256: row rs, col cs) ----
      if (tid < 256) {
        const char* pb = lds + LDS_PART + ((rs * 128 + cs * 8) << 2);
        f32x4 va = *(const f32x4*)pb;
        f32x4 vb = *(const f32x4*)(pb + 16);
        f32x4 sv = va + vb;
        float s = ((sv[0] + sv[1]) + (sv[2] + sv[3])) + b4v;
        if (cs < 12) {
          int byt = rs * 64 + ((cs * 4) ^ ((rs & 3) << 4));
          if (ev == 0) {
            zir = zr + DT * s;
            *(ushort_t*)(lds + LDS_AIN + byt) = f2bf(zir);   // MLP#2 input
          } else {
            float yi = yr + DT * s;
            zr = PP * zir + (1.f - PP) * yi;
            yr = PP * yi + (1.f - PP) * zr;
            *(ushort_t*)(lds + LDS_AIN + byt) = f2bf(yr);    // next MLP#1 input
          }
        }
      }
      __syncthreads();
    }
  }

  // ---- output: action_aug = [z | y] ----
  if (tid < 256 && cs < 12) {
    out[(row0 + rs) * XDIM + cs]      = zr;
    out[(row0 + rs) * XDIM + 12 + cs] = yr;
  }
}

extern "C" void kernel_launch(void* const* d_in, const int* in_sizes, int n_in,
                              void* d_out, int out_size, void* d_ws, size_t ws_size,
                              hipStream_t stream) {
  const float* obs = (const float*)d_in[0];
  const float* x0  = (const float*)d_in[1];
  const float* W1  = (const float*)d_in[2];
  const float* b1  = (const float*)d_in[3];
  const float* W2  = (const float*)d_in[4];
  const float* b2  = (const float*)d_in[5];
  const float* W3  = (const float*)d_in[6];
  const float* b3  = (const float*)d_in[7];
  const float* W4  = (const float*)d_in[8];
  const float* b4  = (const float*)d_in[9];
  const int*   jac = (const int*)d_in[10];
  float* out = (float*)d_out;
  ushort_t* ws = (ushort_t*)d_ws;

  prep_kernel<<<FRAG_BLOCKS + LP_BLOCKS, 256, 0, stream>>>(W1, b1, W2, W3, W4, x0, jac, out, ws);
  flow_main<<<128, 512, 0, stream>>>(obs, x0, W1, b2, b3, b4, ws, out);
}